// Round 1
// 2459.101 us; speedup vs baseline: 3.2290x; 3.2290x over previous
//
#include <hip/hip_runtime.h>
#include <hip/hip_bf16.h>
#include <math.h>

#define VV 32000
#define EE 512
#define DD 1024
#define TE 1024
#define BB 32
#define SS 64
#define TT 48

typedef __attribute__((ext_vector_type(8))) short short8;
typedef __attribute__((ext_vector_type(4))) float f32x4;

__device__ __forceinline__ unsigned short f2b(float x) {
  unsigned int u = __float_as_uint(x);
  u += 0x7fff + ((u >> 16) & 1);
  return (unsigned short)(u >> 16);
}

#define GLDS16(g, l)                                                      \
  __builtin_amdgcn_global_load_lds(                                       \
      (const __attribute__((address_space(1))) void*)(g),                 \
      (__attribute__((address_space(3))) void*)(l), 16, 0, 0)

// ---------------------------------------------------------------------------
// fp32 -> bf16 elementwise, 4-wide, grid-stride
// ---------------------------------------------------------------------------
__global__ void f2b4_k(const float4* __restrict__ src,
                       ushort4* __restrict__ dst, int n4) {
  for (int i = blockIdx.x * 256 + threadIdx.x; i < n4; i += gridDim.x * 256) {
    float4 v = src[i];
    ushort4 o;
    o.x = f2b(v.x); o.y = f2b(v.y); o.z = f2b(v.z); o.w = f2b(v.w);
    dst[i] = o;
  }
}

// ---------------------------------------------------------------------------
// Build W0b[row=d*4+g][k] = bf16( k<1536 ? Wih0[g*1024+d][k] : Whh0[g*1024+d][k-1536] )
// bsum0[row] = bih0[g*1024+d] + bhh0[g*1024+d]
// ---------------------------------------------------------------------------
__global__ void build_w0_k(const float* __restrict__ Wih, const float* __restrict__ Whh,
                           unsigned short* __restrict__ W0b,
                           const float* __restrict__ bih, const float* __restrict__ bhh,
                           float* __restrict__ bsum) {
  const int row = blockIdx.x;            // 0..4095 = d*4+g
  const int d = row >> 2, g = row & 3;
  const int src = g * 1024 + d;
  const float* a = Wih + (size_t)src * 1536;
  const float* b = Whh + (size_t)src * 1024;
  unsigned short* o = W0b + (size_t)row * 2560;
  for (int k = threadIdx.x; k < 1536; k += 256) o[k] = f2b(a[k]);
  for (int k = threadIdx.x; k < 1024; k += 256) o[1536 + k] = f2b(b[k]);
  if (threadIdx.x == 0) bsum[row] = bih[src] + bhh[src];
}

// ---------------------------------------------------------------------------
// Build W1b[row=d*4+g][k] = bf16(Wih1[g*1024+d][k] + Whh1[g*1024+d][k])  (x==h fold)
// ---------------------------------------------------------------------------
__global__ void build_w1_k(const float* __restrict__ Wih, const float* __restrict__ Whh,
                           unsigned short* __restrict__ W1b,
                           const float* __restrict__ bih, const float* __restrict__ bhh,
                           float* __restrict__ bsum) {
  const int row = blockIdx.x;
  const int d = row >> 2, g = row & 3;
  const int src = g * 1024 + d;
  const float* a = Wih + (size_t)src * 1024;
  const float* b = Whh + (size_t)src * 1024;
  unsigned short* o = W1b + (size_t)row * 1024;
  for (int k = threadIdx.x; k < 1024; k += 256) o[k] = f2b(a[k] + b[k]);
  if (threadIdx.x == 0) bsum[row] = bih[src] + bhh[src];
}

// ---------------------------------------------------------------------------
// Gather embeddings for every (t,b) into X0buf[t][b][0:512] (bf16)
// ---------------------------------------------------------------------------
__global__ void emb_k(const float* __restrict__ emb, const int* __restrict__ tgt,
                      unsigned short* __restrict__ X0buf) {
  const int tb = blockIdx.x;   // 0..T*B-1
  const float* src = emb + (size_t)tgt[tb] * EE;
  unsigned short* dst = X0buf + (size_t)tb * 2560;
  const int i = threadIdx.x * 4;
  float4 v = *(const float4*)(src + i);
  dst[i] = f2b(v.x); dst[i + 1] = f2b(v.y); dst[i + 2] = f2b(v.z); dst[i + 3] = f2b(v.w);
}

// ---------------------------------------------------------------------------
// init: X0buf[0] av-part = 0, h-part = bf16(h0); cA = c0
// ---------------------------------------------------------------------------
__global__ void init2_k(const float* __restrict__ h0, const float* __restrict__ c0,
                        unsigned short* __restrict__ X0buf, float* __restrict__ cA) {
  const int i = blockIdx.x * 256 + threadIdx.x;
  if (i < BB * DD) {
    const int b = i >> 10, d = i & 1023;
    unsigned short* r = X0buf + (size_t)b * 2560;
    r[512 + d] = 0;
    r[1536 + d] = f2b(h0[i]);
    cA[i] = c0[i];
  }
}

// ---------------------------------------------------------------------------
// Big MFMA GEMM: C[M,N] fp32 = A[M,K] bf16 @ B[N,K]^T bf16.  128x128 tile,
// 256 threads / 4 waves, each wave 64x64 (4x4 of 16x16x32 MFMA), BK=32.
// blockIdx.x = ROW tile (fast-varying) so consecutive blocks share the B
// col-slice: B fetched ~once from HBM, A (small) stays cache-resident.
// ---------------------------------------------------------------------------
__global__ __launch_bounds__(256) void gemm_big(
    const unsigned short* __restrict__ A, const unsigned short* __restrict__ B,
    float* __restrict__ C, int M, int N, int K) {
  __shared__ unsigned short As[128 * 32];
  __shared__ unsigned short Bs[128 * 32];
  const int tid = threadIdx.x;
  const int wid = tid >> 6, lane = tid & 63;
  const int row0 = blockIdx.x * 128, col0 = blockIdx.y * 128;
  const int wm = (wid >> 1) * 64, wn = (wid & 1) * 64;
  f32x4 acc[4][4] = {};
  const int lr = tid >> 2;           // staging row 0..63
  const int lc = (tid & 3) * 8;      // staging k-offset (bf16)
  const unsigned short* Ag = A + (size_t)(row0 + lr) * K + lc;
  const unsigned short* Bg = B + (size_t)(col0 + lr) * K + lc;
  unsigned short* Al = As + lr * 32 + lc;
  unsigned short* Bl = Bs + lr * 32 + lc;
  const int fr = lane & 15, fq = (lane >> 4) * 8;
  for (int k0 = 0; k0 < K; k0 += 32) {
    GLDS16(Ag + k0, Al);
    GLDS16(Ag + (size_t)64 * K + k0, Al + 64 * 32);
    GLDS16(Bg + k0, Bl);
    GLDS16(Bg + (size_t)64 * K + k0, Bl + 64 * 32);
    __syncthreads();
    short8 af[4], bfr[4];
#pragma unroll
    for (int i = 0; i < 4; ++i) {
      af[i]  = *(const short8*)(As + (wm + i * 16 + fr) * 32 + fq);
      bfr[i] = *(const short8*)(Bs + (wn + i * 16 + fr) * 32 + fq);
    }
#pragma unroll
    for (int i = 0; i < 4; ++i)
#pragma unroll
      for (int j = 0; j < 4; ++j)
        acc[i][j] = __builtin_amdgcn_mfma_f32_16x16x32_bf16(af[i], bfr[j], acc[i][j], 0, 0, 0);
    __syncthreads();
  }
  const int cn = lane & 15, cr = (lane >> 4) * 4;
#pragma unroll
  for (int i = 0; i < 4; ++i)
#pragma unroll
    for (int j = 0; j < 4; ++j)
#pragma unroll
      for (int r = 0; r < 4; ++r)
        C[(size_t)(row0 + wm + i * 16 + cr + r) * N + col0 + wn + j * 16 + cn] = acc[i][j][r];
}

// ---------------------------------------------------------------------------
// Skinny-GEMM core, NO LDS staging: MFMA fragments of A[32,K] and B[16 cols,K]
// are loaded DIRECTLY from row-major global memory (fragment = contiguous 16B
// per lane: row = lane&15, k-off = (lane>>4)*8). 512 threads / 8 waves; wave w
// accumulates over K-chunk [w*K/8,(w+1)*K/8) -> partial 32x16 in acc[2].
// No barriers in the loop; all loads independent -> deep vmcnt pipelining.
// ---------------------------------------------------------------------------
template <int K>
__device__ __forceinline__ void rowgemm8(const unsigned short* __restrict__ A,
                                         const unsigned short* __restrict__ B,
                                         f32x4 acc[2]) {
  const int tid = threadIdx.x;
  const int lane = tid & 63;
  const int fr = lane & 15, fq = (lane >> 4) * 8;
  const int kbeg = (tid >> 6) * (K / 8);
  const unsigned short* a0 = A + (size_t)fr * K + kbeg + fq;
  const unsigned short* a1 = a0 + (size_t)16 * K;
  const unsigned short* b0 = B + (size_t)fr * K + kbeg + fq;
#pragma unroll 4
  for (int k = 0; k < K / 8; k += 32) {
    short8 x0 = *(const short8*)(a0 + k);
    short8 x1 = *(const short8*)(a1 + k);
    short8 y  = *(const short8*)(b0 + k);
    acc[0] = __builtin_amdgcn_mfma_f32_16x16x32_bf16(x0, y, acc[0], 0, 0, 0);
    acc[1] = __builtin_amdgcn_mfma_f32_16x16x32_bf16(x1, y, acc[1], 0, 0, 0);
  }
}

__device__ __forceinline__ float sigm(float x) { return 1.f / (1.f + __expf(-x)); }

// ---------------------------------------------------------------------------
// Cell0: gates = X0 @ W0b^T (K=2560, gate-interleaved cols), LSTM update.
// Grid 256 blocks x 16 cols (4 d-values). Cross-wave reduce via LDS, then
// fused LSTM epilogue. Writes cB (fp32) and h -> X1 (bf16).
// ---------------------------------------------------------------------------
__global__ __launch_bounds__(512) void cell0_k(
    const unsigned short* __restrict__ X0, const unsigned short* __restrict__ W0b,
    const float* __restrict__ bsum, const float* __restrict__ cA,
    float* __restrict__ cB, unsigned short* __restrict__ X1) {
  __shared__ float red[8][32][16];
  const int tid = threadIdx.x, w = tid >> 6, lane = tid & 63;
  const int col0 = blockIdx.x * 16;
  f32x4 acc[2] = {};
  rowgemm8<2560>(X0, W0b + (size_t)col0 * 2560, acc);
  const int cn = lane & 15, cr = (lane >> 4) * 4;
#pragma unroll
  for (int t = 0; t < 2; ++t)
#pragma unroll
    for (int r = 0; r < 4; ++r) red[w][t * 16 + cr + r][cn] = acc[t][r];
  __syncthreads();
  if (tid < 128) {
    const int b = tid >> 2, dl = tid & 3;
    const int d = (col0 >> 2) + dl;
    float g4[4];
#pragma unroll
    for (int g = 0; g < 4; ++g) {
      float s = bsum[col0 + dl * 4 + g];
#pragma unroll
      for (int ww = 0; ww < 8; ++ww) s += red[ww][b][dl * 4 + g];
      g4[g] = s;
    }
    const float cold = cA[b * DD + d];
    const float cnew = sigm(g4[1]) * cold + sigm(g4[0]) * tanhf(g4[2]);
    cB[b * DD + d] = cnew;
    X1[b * DD + d] = f2b(sigm(g4[3]) * tanhf(cnew));
  }
}

// ---------------------------------------------------------------------------
// Cell1: gates = X1 @ W1b^T (K=1024). Writes cA, hA (fp32), h bf16 -> Xc[:,0:1024)
// and X0next[:,1536:2560).
// ---------------------------------------------------------------------------
__global__ __launch_bounds__(512) void cell1_k(
    const unsigned short* __restrict__ X1, const unsigned short* __restrict__ W1b,
    const float* __restrict__ bsum, const float* __restrict__ cB,
    float* __restrict__ cA, float* __restrict__ hA,
    unsigned short* __restrict__ Xc, unsigned short* __restrict__ X0n) {
  __shared__ float red[8][32][16];
  const int tid = threadIdx.x, w = tid >> 6, lane = tid & 63;
  const int col0 = blockIdx.x * 16;
  f32x4 acc[2] = {};
  rowgemm8<1024>(X1, W1b + (size_t)col0 * 1024, acc);
  const int cn = lane & 15, cr = (lane >> 4) * 4;
#pragma unroll
  for (int t = 0; t < 2; ++t)
#pragma unroll
    for (int r = 0; r < 4; ++r) red[w][t * 16 + cr + r][cn] = acc[t][r];
  __syncthreads();
  if (tid < 128) {
    const int b = tid >> 2, dl = tid & 3;
    const int d = (col0 >> 2) + dl;
    float g4[4];
#pragma unroll
    for (int g = 0; g < 4; ++g) {
      float s = bsum[col0 + dl * 4 + g];
#pragma unroll
      for (int ww = 0; ww < 8; ++ww) s += red[ww][b][dl * 4 + g];
      g4[g] = s;
    }
    const float cold = cB[b * DD + d];
    const float cnew = sigm(g4[1]) * cold + sigm(g4[0]) * tanhf(g4[2]);
    cA[b * DD + d] = cnew;
    const float h = sigm(g4[3]) * tanhf(cnew);
    hA[b * DD + d] = h;
    const unsigned short hb = f2b(h);
    Xc[b * 2048 + d] = hb;
    X0n[(size_t)b * 2560 + 1536 + d] = hb;
  }
}

// ---------------------------------------------------------------------------
// Attention (fp32): logits from PA·h, softmax, context = alpha·enc -> bf16
// Xc[:,1024:). float4-vectorized loads throughout.
// ---------------------------------------------------------------------------
__global__ __launch_bounds__(256) void attn_k(
    const float* __restrict__ PA, const float* __restrict__ enc,
    const float* __restrict__ h, unsigned short* __restrict__ Xc) {
  const int b = blockIdx.x;
  __shared__ float hs[DD];
  __shared__ float sm[SS];
  const int tid = threadIdx.x;
  for (int k = tid; k < DD; k += 256) hs[k] = h[b * DD + k];
  __syncthreads();
  const int lane = tid & 63, w = tid >> 6;
#pragma unroll 4
  for (int si = 0; si < 16; ++si) {
    const int s = w * 16 + si;
    const float* pa = PA + ((size_t)s * BB + b) * DD;
    float sum = 0.f;
#pragma unroll
    for (int it = 0; it < 4; ++it) {
      float4 v = *(const float4*)(pa + it * 256 + lane * 4);
      const float* hp = hs + it * 256 + lane * 4;
      sum += v.x * hp[0] + v.y * hp[1] + v.z * hp[2] + v.w * hp[3];
    }
#pragma unroll
    for (int off = 32; off > 0; off >>= 1) sum += __shfl_xor(sum, off);
    if (lane == 0) sm[s] = sum;
  }
  __syncthreads();
  if (tid < 64) {
    float v = sm[tid];
    float m = v;
#pragma unroll
    for (int off = 32; off > 0; off >>= 1) m = fmaxf(m, __shfl_xor(m, off));
    float e = __expf(v - m);
    float s2 = e;
#pragma unroll
    for (int off = 32; off > 0; off >>= 1) s2 += __shfl_xor(s2, off);
    sm[tid] = e / s2;
  }
  __syncthreads();
  const int e0 = tid * 4;
  float a0 = 0.f, a1 = 0.f, a2 = 0.f, a3 = 0.f;
#pragma unroll 8
  for (int s = 0; s < SS; ++s) {
    const float al = sm[s];
    float4 v = *(const float4*)(enc + ((size_t)s * BB + b) * TE + e0);
    a0 += al * v.x; a1 += al * v.y; a2 += al * v.z; a3 += al * v.w;
  }
  ushort4 o;
  o.x = f2b(a0); o.y = f2b(a1); o.z = f2b(a2); o.w = f2b(a3);
  *(ushort4*)(Xc + (size_t)b * 2048 + 1024 + e0) = o;
}

// ---------------------------------------------------------------------------
// Combine: av = tanh(Xc[32,2048] @ Wcb[1024,2048]^T). 64 blocks x 16 cols.
// Writes av bf16 to X0next[:,512:1536) and av_all_t.
// ---------------------------------------------------------------------------
__global__ __launch_bounds__(512) void combine_k(
    const unsigned short* __restrict__ Xc, const unsigned short* __restrict__ Wcb,
    unsigned short* __restrict__ X0n, unsigned short* __restrict__ av_all_t) {
  __shared__ float red[8][32][16];
  const int tid = threadIdx.x, w = tid >> 6, lane = tid & 63;
  const int col0 = blockIdx.x * 16;
  f32x4 acc[2] = {};
  rowgemm8<2048>(Xc, Wcb + (size_t)col0 * 2048, acc);
  const int cn = lane & 15, cr = (lane >> 4) * 4;
#pragma unroll
  for (int t = 0; t < 2; ++t)
#pragma unroll
    for (int r = 0; r < 4; ++r) red[w][t * 16 + cr + r][cn] = acc[t][r];
  __syncthreads();
  const int b = tid >> 4, col = tid & 15;   // 512 threads -> 32x16 outputs
  float s = 0.f;
#pragma unroll
  for (int ww = 0; ww < 8; ++ww) s += red[ww][b][col];
  const int n = col0 + col;
  const unsigned short vb = f2b(tanhf(s));
  X0n[(size_t)b * 2560 + 512 + n] = vb;
  av_all_t[(size_t)b * DD + n] = vb;
}

// ---------------------------------------------------------------------------
extern "C" void kernel_launch(void* const* d_in, const int* in_sizes, int n_in,
                              void* d_out, int out_size, void* d_ws, size_t ws_size,
                              hipStream_t stream) {
  const float* enc   = (const float*)d_in[0];
  const float* h0    = (const float*)d_in[1];
  const float* c0    = (const float*)d_in[2];
  const float* emb   = (const float*)d_in[3];
  const float* Wproj = (const float*)d_in[4];
  const float* Wcomb = (const float*)d_in[5];
  const float* Wout  = (const float*)d_in[6];
  const float* Wih0  = (const float*)d_in[7];
  const float* Whh0  = (const float*)d_in[8];
  const float* bih0  = (const float*)d_in[9];
  const float* bhh0  = (const float*)d_in[10];
  const float* Wih1  = (const float*)d_in[11];
  const float* Whh1  = (const float*)d_in[12];
  const float* bih1  = (const float*)d_in[13];
  const float* bhh1  = (const float*)d_in[14];
  const int*   tgt   = (const int*)d_in[15];
  float* out = (float*)d_out;

  char* p = (char*)d_ws;
  auto alloc = [&](size_t bytes) { char* r = p; p += (bytes + 255) & ~(size_t)255; return r; };
  unsigned short* X0buf   = (unsigned short*)alloc((size_t)(TT + 1) * BB * 2560 * 2);
  unsigned short* X1      = (unsigned short*)alloc((size_t)BB * DD * 2);
  unsigned short* Xc      = (unsigned short*)alloc((size_t)BB * 2048 * 2);
  unsigned short* enc_bf  = (unsigned short*)alloc((size_t)SS * BB * TE * 2);
  unsigned short* Wproj_bf= (unsigned short*)alloc((size_t)DD * TE * 2);
  unsigned short* Wcb     = (unsigned short*)alloc((size_t)DD * 2048 * 2);
  unsigned short* Wout_bf = (unsigned short*)alloc((size_t)VV * DD * 2);
  unsigned short* W0b     = (unsigned short*)alloc((size_t)4096 * 2560 * 2);
  unsigned short* W1b     = (unsigned short*)alloc((size_t)4096 * 1024 * 2);
  unsigned short* av_all  = (unsigned short*)alloc((size_t)TT * BB * DD * 2);
  float* PA    = (float*)alloc((size_t)SS * BB * DD * 4);
  float* cA    = (float*)alloc((size_t)BB * DD * 4);
  float* cB    = (float*)alloc((size_t)BB * DD * 4);
  float* hA    = (float*)alloc((size_t)BB * DD * 4);
  float* bsum0 = (float*)alloc(4096 * 4);
  float* bsum1 = (float*)alloc(4096 * 4);

  // --- one-time prep ---
  f2b4_k<<<2048, 256, 0, stream>>>((const float4*)enc, (ushort4*)enc_bf, SS * BB * TE / 4);
  f2b4_k<<<1024, 256, 0, stream>>>((const float4*)Wproj, (ushort4*)Wproj_bf, DD * TE / 4);
  f2b4_k<<<2048, 256, 0, stream>>>((const float4*)Wcomb, (ushort4*)Wcb, DD * 2048 / 4);
  f2b4_k<<<4096, 256, 0, stream>>>((const float4*)Wout, (ushort4*)Wout_bf, VV * DD / 4);
  build_w0_k<<<4096, 256, 0, stream>>>(Wih0, Whh0, W0b, bih0, bhh0, bsum0);
  build_w1_k<<<4096, 256, 0, stream>>>(Wih1, Whh1, W1b, bih1, bhh1, bsum1);
  emb_k<<<TT * BB, 128, 0, stream>>>(emb, tgt, X0buf);
  init2_k<<<128, 256, 0, stream>>>(h0, c0, X0buf, cA);
  // PA = enc @ Wproj^T  (M=2048, N=1024, K=1024); grid.x = row tiles
  gemm_big<<<dim3((SS * BB) / 128, DD / 128), 256, 0, stream>>>(
      enc_bf, Wproj_bf, PA, SS * BB, DD, TE);

  // --- decode loop ---
  for (int t = 0; t < TT; ++t) {
    const unsigned short* X0 = X0buf + (size_t)t * BB * 2560;
    unsigned short* X0n = X0buf + (size_t)(t + 1) * BB * 2560;
    cell0_k<<<256, 512, 0, stream>>>(X0, W0b, bsum0, cA, cB, X1);
    cell1_k<<<256, 512, 0, stream>>>(X1, W1b, bsum1, cB, cA, hA, Xc, X0n);
    attn_k<<<BB, 256, 0, stream>>>(PA, enc, hA, Xc);
    combine_k<<<64, 512, 0, stream>>>(Xc, Wcb, X0n, av_all + (size_t)t * BB * DD);
  }
  // scores = av_all @ Wout^T  (M=1536, N=32000, K=1024); grid.x = row tiles
  gemm_big<<<dim3((TT * BB) / 128, VV / 128), 256, 0, stream>>>(
      av_all, Wout_bf, out, TT * BB, VV, DD);
}